// Round 3
// baseline (251.019 us; speedup 1.0000x reference)
//
#include <hip/hip_runtime.h>
#include <math.h>

#define DIM 128
#define DFF 512
#define TTW 64
#define NPI 8
#define NTOK 9
#define POOL_HOPS 16
#define HEAD_HOPS 32

typedef __attribute__((ext_vector_type(8))) short short8;
typedef __attribute__((ext_vector_type(4))) float float4v;

__device__ __forceinline__ unsigned short f32_bf16(float f) {
    union { float f; unsigned u; } v; v.f = f;
    unsigned r = v.u + 0x7FFFu + ((v.u >> 16) & 1u);   // RNE
    return (unsigned short)(r >> 16);
}
__device__ __forceinline__ float bf16_f32(unsigned short h) {
    union { unsigned u; float f; } v; v.u = (unsigned)h << 16;
    return v.f;
}

// ================= prep: all-coalesced weight/feature conversion =================
// block ranges: [0,B_HF) hf->bf16 | [B_HF,B_HF+64) W1 transpose tiles |
//               [B_HF+64,B_HF+96) W2 transpose tiles | rest: pack pi|valid
__global__ __launch_bounds__(256)
void prep_k(const float* __restrict__ hf, const float* __restrict__ W1,
            const float* __restrict__ W2, const int* __restrict__ pi,
            const int* __restrict__ stats,
            unsigned short* __restrict__ hf2, unsigned short* __restrict__ w1t,
            unsigned short* __restrict__ w2t, int* __restrict__ cpack,
            int n_hf, int B_HF, int n_pk)
{
    __shared__ float tile[32][33];
    const int b = blockIdx.x, t = threadIdx.x;
    if (b < B_HF) {
        int i = (b * 256 + t) * 4;
        if (i < n_hf) {
            float4v v = *(const float4v*)(hf + i);
            unsigned long long p =  (unsigned long long)f32_bf16(v[0])
                                 | ((unsigned long long)f32_bf16(v[1]) << 16)
                                 | ((unsigned long long)f32_bf16(v[2]) << 32)
                                 | ((unsigned long long)f32_bf16(v[3]) << 48);
            *(unsigned long long*)(hf2 + i) = p;
        }
    } else if (b < B_HF + 64) {
        const int tb = b - B_HF;            // W1 [128][512] -> w1t bf16 [512][128]
        const int r0 = (tb & 3) * 32, c0 = (tb >> 2) * 32;
        const int ty = t >> 3, tx = t & 7;
        *(float4v*)&tile[ty][tx * 4] = *(const float4v*)(W1 + (r0 + ty) * DFF + c0 + tx * 4);
        __syncthreads();
        unsigned long long p = 0;
        #pragma unroll
        for (int j = 0; j < 4; ++j)
            p |= (unsigned long long)f32_bf16(tile[tx * 4 + j][ty]) << (16 * j);
        *(unsigned long long*)(w1t + (c0 + ty) * DIM + r0 + tx * 4) = p;
    } else if (b < B_HF + 96) {
        const int tb = b - B_HF - 64;       // W2 [512][64] -> w2t bf16 [64][512]
        const int r0 = (tb & 15) * 32, c0 = (tb >> 4) * 32;
        const int ty = t >> 3, tx = t & 7;
        *(float4v*)&tile[ty][tx * 4] = *(const float4v*)(W2 + (r0 + ty) * TTW + c0 + tx * 4);
        __syncthreads();
        unsigned long long p = 0;
        #pragma unroll
        for (int j = 0; j < 4; ++j)
            p |= (unsigned long long)f32_bf16(tile[tx * 4 + j][ty]) << (16 * j);
        *(unsigned long long*)(w2t + (c0 + ty) * DFF + r0 + tx * 4) = p;
    } else {
        const int pb = b - (B_HF + 96);
        int i = (pb * 256 + t) * 4;
        if (i < n_pk) {
            int4 p = *(const int4*)(pi + i);
            int4 s = *(const int4*)(stats + i);
            int4 o;
            o.x = p.x | (s.x == -1 ? (int)0x80000000 : 0);
            o.y = p.y | (s.y == -1 ? (int)0x80000000 : 0);
            o.z = p.z | (s.z == -1 ? (int)0x80000000 : 0);
            o.w = p.w | (s.w == -1 ? (int)0x80000000 : 0);
            *(int4*)(cpack + i) = o;
        }
    }
}

// ================= pool: gather + masked attention pooling (no LDS) =================
// 16 lanes per hop; lane l owns dims l*8..l*8+7 (bf16)
__global__ __launch_bounds__(256, 4)
void pool_k(const unsigned short* __restrict__ hf2,
            const float* __restrict__ w_q,
            const int* __restrict__ cpack,
            const int* __restrict__ po,
            unsigned short* __restrict__ pooled,
            int H)
{
    const int t = threadIdx.x;
    const int g = t >> 4, l = t & 15;
    const int hop = blockIdx.x * POOL_HOPS + g;
    if (hop >= H) return;

    float wq[8];
    {
        float4v a = *(const float4v*)(w_q + l * 8);
        float4v b = *(const float4v*)(w_q + l * 8 + 4);
        wq[0]=a[0]; wq[1]=a[1]; wq[2]=a[2]; wq[3]=a[3];
        wq[4]=b[0]; wq[5]=b[1]; wq[6]=b[2]; wq[7]=b[3];
    }
    int idx[NTOK]; bool val[NTOK];
    {
        int4 c0 = *(const int4*)(cpack + hop * NPI);
        int4 c1 = *(const int4*)(cpack + hop * NPI + 4);
        idx[0]=c0.x & 0x7fffffff; val[0]=c0.x >= 0;
        idx[1]=c0.y & 0x7fffffff; val[1]=c0.y >= 0;
        idx[2]=c0.z & 0x7fffffff; val[2]=c0.z >= 0;
        idx[3]=c0.w & 0x7fffffff; val[3]=c0.w >= 0;
        idx[4]=c1.x & 0x7fffffff; val[4]=c1.x >= 0;
        idx[5]=c1.y & 0x7fffffff; val[5]=c1.y >= 0;
        idx[6]=c1.z & 0x7fffffff; val[6]=c1.z >= 0;
        idx[7]=c1.w & 0x7fffffff; val[7]=c1.w >= 0;
        idx[8]=po[hop]; val[8]=true;
    }
    short8 tok[NTOK];
    #pragma unroll
    for (int p = 0; p < NTOK; ++p)
        tok[p] = *(const short8*)(hf2 + (size_t)idx[p] * DIM + l * 8);

    float sc[NTOK];
    #pragma unroll
    for (int p = 0; p < NTOK; ++p) {
        float s = 0.f;
        #pragma unroll
        for (int j = 0; j < 8; ++j)
            s += bf16_f32((unsigned short)tok[p][j]) * wq[j];
        sc[p] = s;
    }
    #pragma unroll
    for (int m = 1; m < 16; m <<= 1) {
        #pragma unroll
        for (int p = 0; p < NTOK; ++p) sc[p] += __shfl_xor(sc[p], m);
    }
    const float isd = 0.08838834764831845f;   // 1/sqrt(128)
    float mx = -1e30f;
    #pragma unroll
    for (int p = 0; p < NTOK; ++p) {
        sc[p] = val[p] ? sc[p] * isd : -1e30f;
        mx = fmaxf(mx, sc[p]);
    }
    float se = 0.f;
    #pragma unroll
    for (int p = 0; p < NTOK; ++p) { sc[p] = __expf(sc[p] - mx); se += sc[p]; }
    const float inv = 1.f / se;
    float acc[8] = {0,0,0,0,0,0,0,0};
    #pragma unroll
    for (int p = 0; p < NTOK; ++p) {
        float a = sc[p] * inv;
        #pragma unroll
        for (int j = 0; j < 8; ++j)
            acc[j] += a * bf16_f32((unsigned short)tok[p][j]);
    }
    unsigned long long p0 = 0, p1 = 0;
    #pragma unroll
    for (int j = 0; j < 4; ++j) p0 |= (unsigned long long)f32_bf16(acc[j])     << (16 * j);
    #pragma unroll
    for (int j = 0; j < 4; ++j) p1 |= (unsigned long long)f32_bf16(acc[4 + j]) << (16 * j);
    unsigned long long* dst = (unsigned long long*)(pooled + (size_t)hop * DIM + l * 8);
    dst[0] = p0; dst[1] = p1;
}

// ================= head: GEMM1 + ReLU + LN + GEMM2 =================
__global__ __launch_bounds__(256, 4)
void head_k(const unsigned short* __restrict__ pooled,
            const unsigned short* __restrict__ w1t,     // bf16 [512][128]
            const float* __restrict__ b1,
            const float* __restrict__ gamma,
            const float* __restrict__ beta,
            const unsigned short* __restrict__ w2t,     // bf16 [64][512]
            const float* __restrict__ b2,
            float* __restrict__ out,
            int H)
{
    __shared__ unsigned short Hsm[HEAD_HOPS][DFF + 8];  // stride 520: 16B-aligned rows

    const int t    = threadIdx.x;
    const int lane = t & 63;
    const int w    = t >> 6;
    const int row  = lane & 15;
    const int quad = lane >> 4;
    const int hop0 = blockIdx.x * HEAD_HOPS;

    // -------- GEMM1 (swapped: A=W1T rows=out-dims, B=pooled^T cols=hops) --------
    {
        float4v acc1[8][2];
        #pragma unroll
        for (int mt = 0; mt < 8; ++mt)
            #pragma unroll
            for (int ht = 0; ht < 2; ++ht)
                acc1[mt][ht] = (float4v){0.f, 0.f, 0.f, 0.f};

        #pragma unroll
        for (int ks = 0; ks < 4; ++ks) {
            const int k0 = ks * 32 + quad * 8;
            short8 bfr[2];
            #pragma unroll
            for (int ht = 0; ht < 2; ++ht) {
                int hp = hop0 + ht * 16 + row;
                if (hp >= H) hp = H - 1;    // clamped read; store is guarded
                bfr[ht] = *(const short8*)(pooled + (size_t)hp * DIM + k0);
            }
            #pragma unroll
            for (int mt = 0; mt < 8; ++mt) {
                short8 afr = *(const short8*)(w1t + (size_t)(w * 128 + mt * 16 + row) * DIM + k0);
                #pragma unroll
                for (int ht = 0; ht < 2; ++ht)
                    acc1[mt][ht] = __builtin_amdgcn_mfma_f32_16x16x32_bf16(
                        afr, bfr[ht], acc1[mt][ht], 0, 0, 0);
            }
        }
        #pragma unroll
        for (int mt = 0; mt < 8; ++mt) {
            const int nb = w * 128 + mt * 16 + quad * 4;
            const float4v bias = *(const float4v*)(b1 + nb);
            #pragma unroll
            for (int ht = 0; ht < 2; ++ht) {
                unsigned long long p = 0;
                #pragma unroll
                for (int r = 0; r < 4; ++r) {
                    float v = fmaxf(acc1[mt][ht][r] + bias[r], 0.f);
                    p |= (unsigned long long)f32_bf16(v) << (16 * r);
                }
                *(unsigned long long*)&Hsm[ht * 16 + row][nb] = p;
            }
        }
    }
    __syncthreads();

    // -------- LayerNorm (8 lanes per row, in place) --------
    {
        const int r = t >> 3;
        const int s = t & 7;
        float sum = 0.f, ssq = 0.f;
        #pragma unroll
        for (int k = 0; k < 8; ++k) {
            short8 hv = *(const short8*)&Hsm[r][s * 8 + k * 64];
            #pragma unroll
            for (int e = 0; e < 8; ++e) {
                float v = bf16_f32((unsigned short)hv[e]);
                sum += v; ssq += v * v;
            }
        }
        #pragma unroll
        for (int m = 1; m < 8; m <<= 1) {
            sum += __shfl_xor(sum, m);
            ssq += __shfl_xor(ssq, m);
        }
        const float invn = 1.f / (float)DFF;
        float mu  = sum * invn;
        float var = ssq * invn - mu * mu;
        float rs  = rsqrtf(var + 1e-5f);
        #pragma unroll
        for (int k = 0; k < 8; ++k) {
            const int col = s * 8 + k * 64;
            short8 hv = *(const short8*)&Hsm[r][col];
            float4v g0 = *(const float4v*)(gamma + col);
            float4v g1 = *(const float4v*)(gamma + col + 4);
            float4v be0 = *(const float4v*)(beta + col);
            float4v be1 = *(const float4v*)(beta + col + 4);
            unsigned long long q0 = 0, q1 = 0;
            #pragma unroll
            for (int e = 0; e < 4; ++e) {
                float tg = rs * g0[e];
                float o  = bf16_f32((unsigned short)hv[e]) * tg + (be0[e] - mu * tg);
                q0 |= (unsigned long long)f32_bf16(o) << (16 * e);
            }
            #pragma unroll
            for (int e = 0; e < 4; ++e) {
                float tg = rs * g1[e];
                float o  = bf16_f32((unsigned short)hv[4 + e]) * tg + (be1[e] - mu * tg);
                q1 |= (unsigned long long)f32_bf16(o) << (16 * e);
            }
            *(unsigned long long*)&Hsm[r][col]     = q0;
            *(unsigned long long*)&Hsm[r][col + 4] = q1;
        }
    }
    __syncthreads();

    // -------- GEMM2 (A=Hs [hop][k] LDS, B=w2t [tt][k] global) --------
    {
        float4v acc2[2];
        acc2[0] = (float4v){0.f,0.f,0.f,0.f};
        acc2[1] = (float4v){0.f,0.f,0.f,0.f};
        #pragma unroll
        for (int ks = 0; ks < 16; ++ks) {
            const int k0 = ks * 32 + quad * 8;
            short8 bfr = *(const short8*)(w2t + (size_t)(w * 16 + row) * DFF + k0);
            #pragma unroll
            for (int mt = 0; mt < 2; ++mt) {
                short8 afr = *(const short8*)&Hsm[mt * 16 + row][k0];
                acc2[mt] = __builtin_amdgcn_mfma_f32_16x16x32_bf16(
                    afr, bfr, acc2[mt], 0, 0, 0);
            }
        }
        const float bb = b2[w * 16 + row];
        #pragma unroll
        for (int mt = 0; mt < 2; ++mt) {
            #pragma unroll
            for (int r = 0; r < 4; ++r) {
                int hop = hop0 + mt * 16 + quad * 4 + r;
                if (hop < H)
                    out[(size_t)hop * TTW + w * 16 + row] = acc2[mt][r] + bb;
            }
        }
    }
}

extern "C" void kernel_launch(void* const* d_in, const int* in_sizes, int n_in,
                              void* d_out, int out_size, void* d_ws, size_t ws_size,
                              hipStream_t stream) {
    const float* hf    = (const float*)d_in[0];
    const float* w_q   = (const float*)d_in[1];
    const float* W1    = (const float*)d_in[2];
    const float* b1    = (const float*)d_in[3];
    const float* gamma = (const float*)d_in[4];
    const float* beta  = (const float*)d_in[5];
    const float* W2    = (const float*)d_in[6];
    const float* b2    = (const float*)d_in[7];
    const int* pi      = (const int*)d_in[8];
    const int* stats   = (const int*)d_in[9];
    const int* po      = (const int*)d_in[10];
    float* out         = (float*)d_out;

    const int n_hf = in_sizes[0];           // N_NODES*128
    const int H    = in_sizes[10];
    const int n_pk = H * NPI;
    const int Hpad = ((H + HEAD_HOPS - 1) / HEAD_HOPS) * HEAD_HOPS;

    // ws layout (256B-aligned chunks)
    char* ws = (char*)d_ws;
    unsigned short* w1t    = (unsigned short*)ws;                       // 128KB
    unsigned short* w2t    = (unsigned short*)(ws + 131072);            // 64KB
    unsigned short* hf2    = (unsigned short*)(ws + 196608);            // n_hf*2
    size_t off_cp = 196608 + ((size_t)n_hf * 2 + 255) / 256 * 256;
    int*            cpack  = (int*)(ws + off_cp);                       // n_pk*4
    size_t off_pl = off_cp + ((size_t)n_pk * 4 + 255) / 256 * 256;
    unsigned short* pooled = (unsigned short*)(ws + off_pl);            // Hpad*128*2

    const int B_HF = (n_hf + 1023) / 1024;
    const int B_PK = (n_pk + 1023) / 1024;
    const int prep_blocks = B_HF + 96 + B_PK;

    hipLaunchKernelGGL(prep_k, dim3(prep_blocks), dim3(256), 0, stream,
                       hf, W1, W2, pi, stats, hf2, w1t, w2t, cpack,
                       n_hf, B_HF, n_pk);
    hipLaunchKernelGGL(pool_k, dim3((H + POOL_HOPS - 1) / POOL_HOPS), dim3(256), 0, stream,
                       hf2, w_q, cpack, po, pooled, H);
    hipLaunchKernelGGL(head_k, dim3(Hpad / HEAD_HOPS), dim3(256), 0, stream,
                       pooled, w1t, b1, gamma, beta, w2t, b2, out, H);
}

// Round 4
// 225.786 us; speedup vs baseline: 1.1118x; 1.1118x over previous
//
#include <hip/hip_runtime.h>
#include <math.h>

#define DIM 128
#define DFF 512
#define TTW 64
#define NPI 8
#define NTOK 9
#define POOL_HOPS 16
#define HEAD_HOPS 32

typedef __attribute__((ext_vector_type(8))) short short8;
typedef __attribute__((ext_vector_type(4))) float float4v;

__device__ __forceinline__ unsigned short f32_bf16(float f) {
    union { float f; unsigned u; } v; v.f = f;
    unsigned r = v.u + 0x7FFFu + ((v.u >> 16) & 1u);   // RNE
    return (unsigned short)(r >> 16);
}
__device__ __forceinline__ float bf16_f32(unsigned short h) {
    union { unsigned u; float f; } v; v.u = (unsigned)h << 16;
    return v.f;
}

// ================= prep: all-coalesced weight/feature conversion =================
__global__ __launch_bounds__(256)
void prep_k(const float* __restrict__ hf, const float* __restrict__ W1,
            const float* __restrict__ W2, const int* __restrict__ pi,
            const int* __restrict__ stats,
            unsigned short* __restrict__ hf2, unsigned short* __restrict__ w1t,
            unsigned short* __restrict__ w2t, int* __restrict__ cpack,
            int n_hf, int B_HF, int n_pk)
{
    __shared__ float tile[32][33];
    const int b = blockIdx.x, t = threadIdx.x;
    if (b < B_HF) {
        int i = (b * 256 + t) * 4;
        if (i < n_hf) {
            float4v v = *(const float4v*)(hf + i);
            unsigned long long p =  (unsigned long long)f32_bf16(v[0])
                                 | ((unsigned long long)f32_bf16(v[1]) << 16)
                                 | ((unsigned long long)f32_bf16(v[2]) << 32)
                                 | ((unsigned long long)f32_bf16(v[3]) << 48);
            *(unsigned long long*)(hf2 + i) = p;
        }
    } else if (b < B_HF + 64) {
        const int tb = b - B_HF;            // W1 [128][512] -> w1t bf16 [512][128]
        const int r0 = (tb & 3) * 32, c0 = (tb >> 2) * 32;
        const int ty = t >> 3, tx = t & 7;
        *(float4v*)&tile[ty][tx * 4] = *(const float4v*)(W1 + (r0 + ty) * DFF + c0 + tx * 4);
        __syncthreads();
        unsigned long long p = 0;
        #pragma unroll
        for (int j = 0; j < 4; ++j)
            p |= (unsigned long long)f32_bf16(tile[tx * 4 + j][ty]) << (16 * j);
        *(unsigned long long*)(w1t + (c0 + ty) * DIM + r0 + tx * 4) = p;
    } else if (b < B_HF + 96) {
        const int tb = b - B_HF - 64;       // W2 [512][64] -> w2t bf16 [64][512]
        const int r0 = (tb & 15) * 32, c0 = (tb >> 4) * 32;
        const int ty = t >> 3, tx = t & 7;
        *(float4v*)&tile[ty][tx * 4] = *(const float4v*)(W2 + (r0 + ty) * TTW + c0 + tx * 4);
        __syncthreads();
        unsigned long long p = 0;
        #pragma unroll
        for (int j = 0; j < 4; ++j)
            p |= (unsigned long long)f32_bf16(tile[tx * 4 + j][ty]) << (16 * j);
        *(unsigned long long*)(w2t + (c0 + ty) * DFF + r0 + tx * 4) = p;
    } else {
        const int pb = b - (B_HF + 96);
        int i = (pb * 256 + t) * 4;
        if (i < n_pk) {
            int4 p = *(const int4*)(pi + i);
            int4 s = *(const int4*)(stats + i);
            int4 o;
            o.x = p.x | (s.x == -1 ? (int)0x80000000 : 0);
            o.y = p.y | (s.y == -1 ? (int)0x80000000 : 0);
            o.z = p.z | (s.z == -1 ? (int)0x80000000 : 0);
            o.w = p.w | (s.w == -1 ? (int)0x80000000 : 0);
            *(int4*)(cpack + i) = o;
        }
    }
}

// ================= pool: gather + masked attention pooling (no LDS) =================
__global__ __launch_bounds__(256, 4)
void pool_k(const unsigned short* __restrict__ hf2,
            const float* __restrict__ w_q,
            const int* __restrict__ cpack,
            const int* __restrict__ po,
            unsigned short* __restrict__ pooled,
            int H)
{
    const int t = threadIdx.x;
    const int g = t >> 4, l = t & 15;
    const int hop = blockIdx.x * POOL_HOPS + g;
    if (hop >= H) return;

    float wq[8];
    {
        float4v a = *(const float4v*)(w_q + l * 8);
        float4v b = *(const float4v*)(w_q + l * 8 + 4);
        wq[0]=a[0]; wq[1]=a[1]; wq[2]=a[2]; wq[3]=a[3];
        wq[4]=b[0]; wq[5]=b[1]; wq[6]=b[2]; wq[7]=b[3];
    }
    int idx[NTOK]; bool val[NTOK];
    {
        int4 c0 = *(const int4*)(cpack + hop * NPI);
        int4 c1 = *(const int4*)(cpack + hop * NPI + 4);
        idx[0]=c0.x & 0x7fffffff; val[0]=c0.x >= 0;
        idx[1]=c0.y & 0x7fffffff; val[1]=c0.y >= 0;
        idx[2]=c0.z & 0x7fffffff; val[2]=c0.z >= 0;
        idx[3]=c0.w & 0x7fffffff; val[3]=c0.w >= 0;
        idx[4]=c1.x & 0x7fffffff; val[4]=c1.x >= 0;
        idx[5]=c1.y & 0x7fffffff; val[5]=c1.y >= 0;
        idx[6]=c1.z & 0x7fffffff; val[6]=c1.z >= 0;
        idx[7]=c1.w & 0x7fffffff; val[7]=c1.w >= 0;
        idx[8]=po[hop]; val[8]=true;
    }
    short8 tok[NTOK];
    #pragma unroll
    for (int p = 0; p < NTOK; ++p)
        tok[p] = *(const short8*)(hf2 + (size_t)idx[p] * DIM + l * 8);

    float sc[NTOK];
    #pragma unroll
    for (int p = 0; p < NTOK; ++p) {
        float s = 0.f;
        #pragma unroll
        for (int j = 0; j < 8; ++j)
            s += bf16_f32((unsigned short)tok[p][j]) * wq[j];
        sc[p] = s;
    }
    #pragma unroll
    for (int m = 1; m < 16; m <<= 1) {
        #pragma unroll
        for (int p = 0; p < NTOK; ++p) sc[p] += __shfl_xor(sc[p], m);
    }
    const float isd = 0.08838834764831845f;   // 1/sqrt(128)
    float mx = -1e30f;
    #pragma unroll
    for (int p = 0; p < NTOK; ++p) {
        sc[p] = val[p] ? sc[p] * isd : -1e30f;
        mx = fmaxf(mx, sc[p]);
    }
    float se = 0.f;
    #pragma unroll
    for (int p = 0; p < NTOK; ++p) { sc[p] = __expf(sc[p] - mx); se += sc[p]; }
    const float inv = 1.f / se;
    float acc[8] = {0,0,0,0,0,0,0,0};
    #pragma unroll
    for (int p = 0; p < NTOK; ++p) {
        float a = sc[p] * inv;
        #pragma unroll
        for (int j = 0; j < 8; ++j)
            acc[j] += a * bf16_f32((unsigned short)tok[p][j]);
    }
    unsigned long long p0 = 0, p1 = 0;
    #pragma unroll
    for (int j = 0; j < 4; ++j) p0 |= (unsigned long long)f32_bf16(acc[j])     << (16 * j);
    #pragma unroll
    for (int j = 0; j < 4; ++j) p1 |= (unsigned long long)f32_bf16(acc[4 + j]) << (16 * j);
    unsigned long long* dst = (unsigned long long*)(pooled + (size_t)hop * DIM + l * 8);
    dst[0] = p0; dst[1] = p1;
}

// ================= head: GEMM1 + ReLU + LN + GEMM2 (spill-free: mt-outer) =================
__global__ __launch_bounds__(256, 3)
void head_k(const unsigned short* __restrict__ pooled,
            const unsigned short* __restrict__ w1t,     // bf16 [512][128]
            const float* __restrict__ b1,
            const float* __restrict__ gamma,
            const float* __restrict__ beta,
            const unsigned short* __restrict__ w2t,     // bf16 [64][512]
            const float* __restrict__ b2,
            float* __restrict__ out,
            int H)
{
    __shared__ unsigned short Hsm[HEAD_HOPS][DFF + 8];  // stride 520: 16B-aligned rows

    const int t    = threadIdx.x;
    const int lane = t & 63;
    const int w    = t >> 6;
    const int row  = lane & 15;
    const int quad = lane >> 4;
    const int hop0 = blockIdx.x * HEAD_HOPS;

    // -------- GEMM1: A=W1T rows (out-dims), B=pooled^T (hops). mt-outer, acc[2] live --------
    {
        short8 bfr[2][4];                 // B-fragments persist across all mt (32 VGPRs)
        #pragma unroll
        for (int ks = 0; ks < 4; ++ks) {
            const int k0 = ks * 32 + quad * 8;
            #pragma unroll
            for (int ht = 0; ht < 2; ++ht) {
                int hp = hop0 + ht * 16 + row;
                if (hp >= H) hp = H - 1;      // clamped read; out store is guarded
                bfr[ht][ks] = *(const short8*)(pooled + (size_t)hp * DIM + k0);
            }
        }
        #pragma unroll
        for (int mt = 0; mt < 8; ++mt) {
            float4v acc0 = (float4v){0.f, 0.f, 0.f, 0.f};
            float4v acc1 = (float4v){0.f, 0.f, 0.f, 0.f};
            const unsigned short* wrow = w1t + (size_t)(w * 128 + mt * 16 + row) * DIM;
            #pragma unroll
            for (int ks = 0; ks < 4; ++ks) {
                short8 afr = *(const short8*)(wrow + ks * 32 + quad * 8);
                acc0 = __builtin_amdgcn_mfma_f32_16x16x32_bf16(afr, bfr[0][ks], acc0, 0, 0, 0);
                acc1 = __builtin_amdgcn_mfma_f32_16x16x32_bf16(afr, bfr[1][ks], acc1, 0, 0, 0);
            }
            const int nb = w * 128 + mt * 16 + quad * 4;
            const float4v bias = *(const float4v*)(b1 + nb);
            unsigned long long p0 = 0, p1 = 0;
            #pragma unroll
            for (int r = 0; r < 4; ++r) {
                float v0 = fmaxf(acc0[r] + bias[r], 0.f);
                float v1 = fmaxf(acc1[r] + bias[r], 0.f);
                p0 |= (unsigned long long)f32_bf16(v0) << (16 * r);
                p1 |= (unsigned long long)f32_bf16(v1) << (16 * r);
            }
            *(unsigned long long*)&Hsm[row][nb]      = p0;
            *(unsigned long long*)&Hsm[16 + row][nb] = p1;
        }
    }
    __syncthreads();

    // -------- LayerNorm (8 lanes per row, in place) --------
    {
        const int r = t >> 3;
        const int s = t & 7;
        float sum = 0.f, ssq = 0.f;
        #pragma unroll
        for (int k = 0; k < 8; ++k) {
            short8 hv = *(const short8*)&Hsm[r][s * 8 + k * 64];
            #pragma unroll
            for (int e = 0; e < 8; ++e) {
                float v = bf16_f32((unsigned short)hv[e]);
                sum += v; ssq += v * v;
            }
        }
        #pragma unroll
        for (int m = 1; m < 8; m <<= 1) {
            sum += __shfl_xor(sum, m);
            ssq += __shfl_xor(ssq, m);
        }
        const float invn = 1.f / (float)DFF;
        float mu  = sum * invn;
        float var = ssq * invn - mu * mu;
        float rs  = rsqrtf(var + 1e-5f);
        #pragma unroll
        for (int k = 0; k < 8; ++k) {
            const int col = s * 8 + k * 64;
            short8 hv = *(const short8*)&Hsm[r][col];
            float4v g0 = *(const float4v*)(gamma + col);
            float4v g1 = *(const float4v*)(gamma + col + 4);
            float4v be0 = *(const float4v*)(beta + col);
            float4v be1 = *(const float4v*)(beta + col + 4);
            unsigned long long q0 = 0, q1 = 0;
            #pragma unroll
            for (int e = 0; e < 4; ++e) {
                float tg = rs * g0[e];
                float o  = bf16_f32((unsigned short)hv[e]) * tg + (be0[e] - mu * tg);
                q0 |= (unsigned long long)f32_bf16(o) << (16 * e);
            }
            #pragma unroll
            for (int e = 0; e < 4; ++e) {
                float tg = rs * g1[e];
                float o  = bf16_f32((unsigned short)hv[4 + e]) * tg + (be1[e] - mu * tg);
                q1 |= (unsigned long long)f32_bf16(o) << (16 * e);
            }
            *(unsigned long long*)&Hsm[r][col]     = q0;
            *(unsigned long long*)&Hsm[r][col + 4] = q1;
        }
    }
    __syncthreads();

    // -------- GEMM2 (A=Hs [hop][k] LDS, B=w2t [tt][k] global) --------
    {
        float4v acc2[2];
        acc2[0] = (float4v){0.f,0.f,0.f,0.f};
        acc2[1] = (float4v){0.f,0.f,0.f,0.f};
        #pragma unroll
        for (int ks = 0; ks < 16; ++ks) {
            const int k0 = ks * 32 + quad * 8;
            short8 bfr = *(const short8*)(w2t + (size_t)(w * 16 + row) * DFF + k0);
            #pragma unroll
            for (int mt = 0; mt < 2; ++mt) {
                short8 afr = *(const short8*)&Hsm[mt * 16 + row][k0];
                acc2[mt] = __builtin_amdgcn_mfma_f32_16x16x32_bf16(
                    afr, bfr, acc2[mt], 0, 0, 0);
            }
        }
        const float bb = b2[w * 16 + row];
        #pragma unroll
        for (int mt = 0; mt < 2; ++mt) {
            #pragma unroll
            for (int r = 0; r < 4; ++r) {
                int hop = hop0 + mt * 16 + quad * 4 + r;
                if (hop < H)
                    out[(size_t)hop * TTW + w * 16 + row] = acc2[mt][r] + bb;
            }
        }
    }
}

extern "C" void kernel_launch(void* const* d_in, const int* in_sizes, int n_in,
                              void* d_out, int out_size, void* d_ws, size_t ws_size,
                              hipStream_t stream) {
    const float* hf    = (const float*)d_in[0];
    const float* w_q   = (const float*)d_in[1];
    const float* W1    = (const float*)d_in[2];
    const float* b1    = (const float*)d_in[3];
    const float* gamma = (const float*)d_in[4];
    const float* beta  = (const float*)d_in[5];
    const float* W2    = (const float*)d_in[6];
    const float* b2    = (const float*)d_in[7];
    const int* pi      = (const int*)d_in[8];
    const int* stats   = (const int*)d_in[9];
    const int* po      = (const int*)d_in[10];
    float* out         = (float*)d_out;

    const int n_hf = in_sizes[0];           // N_NODES*128
    const int H    = in_sizes[10];
    const int n_pk = H * NPI;
    const int Hpad = ((H + HEAD_HOPS - 1) / HEAD_HOPS) * HEAD_HOPS;

    // ws layout (256B-aligned chunks)
    char* ws = (char*)d_ws;
    unsigned short* w1t    = (unsigned short*)ws;                       // 128KB
    unsigned short* w2t    = (unsigned short*)(ws + 131072);            // 64KB
    unsigned short* hf2    = (unsigned short*)(ws + 196608);            // n_hf*2
    size_t off_cp = 196608 + ((size_t)n_hf * 2 + 255) / 256 * 256;
    int*            cpack  = (int*)(ws + off_cp);                       // n_pk*4
    size_t off_pl = off_cp + ((size_t)n_pk * 4 + 255) / 256 * 256;
    unsigned short* pooled = (unsigned short*)(ws + off_pl);            // Hpad*128*2

    const int B_HF = (n_hf + 1023) / 1024;
    const int B_PK = (n_pk + 1023) / 1024;
    const int prep_blocks = B_HF + 96 + B_PK;

    hipLaunchKernelGGL(prep_k, dim3(prep_blocks), dim3(256), 0, stream,
                       hf, W1, W2, pi, stats, hf2, w1t, w2t, cpack,
                       n_hf, B_HF, n_pk);
    hipLaunchKernelGGL(pool_k, dim3((H + POOL_HOPS - 1) / POOL_HOPS), dim3(256), 0, stream,
                       hf2, w_q, cpack, po, pooled, H);
    hipLaunchKernelGGL(head_k, dim3(Hpad / HEAD_HOPS), dim3(256), 0, stream,
                       pooled, w1t, b1, gamma, beta, w2t, b2, out, H);
}

// Round 5
// 225.714 us; speedup vs baseline: 1.1121x; 1.0003x over previous
//
#include <hip/hip_runtime.h>
#include <hip/hip_bf16.h>
#include <math.h>

#define DIM 128
#define DFF 512
#define TTW 64
#define NPI 8
#define NTOK 9
#define POOL_HOPS 8
#define HEAD_HOPS 32

typedef __attribute__((ext_vector_type(8))) short short8;
typedef __attribute__((ext_vector_type(4))) float float4v;

__device__ __forceinline__ unsigned short f32_bf16(float f) {
    union { float f; unsigned u; } v; v.f = f;
    unsigned r = v.u + 0x7FFFu + ((v.u >> 16) & 1u);   // RNE
    return (unsigned short)(r >> 16);
}
__device__ __forceinline__ float bf16lo_f32(unsigned u) {   // low 16 bits -> f32
    union { unsigned u; float f; } v; v.u = u << 16;
    return v.f;
}
__device__ __forceinline__ float bf16hi_f32(unsigned u) {   // high 16 bits -> f32
    union { unsigned u; float f; } v; v.u = u & 0xffff0000u;
    return v.f;
}
__device__ __forceinline__ unsigned pk_bf16(float a, float b) {  // -> a | b<<16
    __hip_bfloat162 h = __float22bfloat162_rn(float2{a, b});
    union { __hip_bfloat162 h; unsigned u; } cv; cv.h = h;
    return cv.u;
}

// ================= prep: all-coalesced weight/feature conversion =================
__global__ __launch_bounds__(256)
void prep_k(const float* __restrict__ hf, const float* __restrict__ W1,
            const float* __restrict__ W2, const int* __restrict__ pi,
            const int* __restrict__ stats,
            unsigned short* __restrict__ hf2, unsigned short* __restrict__ w1t,
            unsigned short* __restrict__ w2t, int* __restrict__ cpack,
            int n_hf, int B_HF, int n_pk)
{
    __shared__ float tile[32][33];
    const int b = blockIdx.x, t = threadIdx.x;
    if (b < B_HF) {
        int i = (b * 256 + t) * 4;
        if (i < n_hf) {
            float4v v = *(const float4v*)(hf + i);
            uint2 o;
            o.x = pk_bf16(v[0], v[1]);
            o.y = pk_bf16(v[2], v[3]);
            *(uint2*)(hf2 + i) = o;
        }
    } else if (b < B_HF + 64) {
        const int tb = b - B_HF;            // W1 [128][512] -> w1t bf16 [512][128]
        const int r0 = (tb & 3) * 32, c0 = (tb >> 2) * 32;
        const int ty = t >> 3, tx = t & 7;
        *(float4v*)&tile[ty][tx * 4] = *(const float4v*)(W1 + (r0 + ty) * DFF + c0 + tx * 4);
        __syncthreads();
        uint2 o;
        o.x = pk_bf16(tile[tx * 4 + 0][ty], tile[tx * 4 + 1][ty]);
        o.y = pk_bf16(tile[tx * 4 + 2][ty], tile[tx * 4 + 3][ty]);
        *(uint2*)(w1t + (c0 + ty) * DIM + r0 + tx * 4) = o;
    } else if (b < B_HF + 96) {
        const int tb = b - B_HF - 64;       // W2 [512][64] -> w2t bf16 [64][512]
        const int r0 = (tb & 15) * 32, c0 = (tb >> 4) * 32;
        const int ty = t >> 3, tx = t & 7;
        *(float4v*)&tile[ty][tx * 4] = *(const float4v*)(W2 + (r0 + ty) * TTW + c0 + tx * 4);
        __syncthreads();
        uint2 o;
        o.x = pk_bf16(tile[tx * 4 + 0][ty], tile[tx * 4 + 1][ty]);
        o.y = pk_bf16(tile[tx * 4 + 2][ty], tile[tx * 4 + 3][ty]);
        *(uint2*)(w2t + (c0 + ty) * DFF + r0 + tx * 4) = o;
    } else {
        const int pb = b - (B_HF + 96);
        int i = (pb * 256 + t) * 4;
        if (i < n_pk) {
            int4 p = *(const int4*)(pi + i);
            int4 s = *(const int4*)(stats + i);
            int4 o;
            o.x = p.x | (s.x == -1 ? (int)0x80000000 : 0);
            o.y = p.y | (s.y == -1 ? (int)0x80000000 : 0);
            o.z = p.z | (s.z == -1 ? (int)0x80000000 : 0);
            o.w = p.w | (s.w == -1 ? (int)0x80000000 : 0);
            *(int4*)(cpack + i) = o;
        }
    }
}

// ================= pool: gather + attention pooling (32 lanes/hop, high occ) =================
__global__ __launch_bounds__(256, 6)
void pool_k(const unsigned short* __restrict__ hf2,
            const float* __restrict__ w_q,
            const int* __restrict__ cpack,
            const int* __restrict__ po,
            unsigned short* __restrict__ pooled,
            int H)
{
    const int t = threadIdx.x;
    const int g = t >> 5, l = t & 31;       // lane l owns dims 4l..4l+3
    const int hop = blockIdx.x * POOL_HOPS + g;
    if (hop >= H) return;

    const float4v wq4 = *(const float4v*)(w_q + l * 4);

    int idx[NTOK]; bool val[NTOK];
    {
        int4 c0 = *(const int4*)(cpack + hop * NPI);
        int4 c1 = *(const int4*)(cpack + hop * NPI + 4);
        idx[0]=c0.x & 0x7fffffff; val[0]=c0.x >= 0;
        idx[1]=c0.y & 0x7fffffff; val[1]=c0.y >= 0;
        idx[2]=c0.z & 0x7fffffff; val[2]=c0.z >= 0;
        idx[3]=c0.w & 0x7fffffff; val[3]=c0.w >= 0;
        idx[4]=c1.x & 0x7fffffff; val[4]=c1.x >= 0;
        idx[5]=c1.y & 0x7fffffff; val[5]=c1.y >= 0;
        idx[6]=c1.z & 0x7fffffff; val[6]=c1.z >= 0;
        idx[7]=c1.w & 0x7fffffff; val[7]=c1.w >= 0;
        idx[8]=po[hop]; val[8]=true;
    }
    uint2 tu[NTOK];
    #pragma unroll
    for (int p = 0; p < NTOK; ++p)
        tu[p] = *(const uint2*)(hf2 + (size_t)idx[p] * DIM + l * 4);

    float tok[NTOK][4];
    #pragma unroll
    for (int p = 0; p < NTOK; ++p) {
        tok[p][0] = bf16lo_f32(tu[p].x);
        tok[p][1] = bf16hi_f32(tu[p].x);
        tok[p][2] = bf16lo_f32(tu[p].y);
        tok[p][3] = bf16hi_f32(tu[p].y);
    }
    float sc[NTOK];
    #pragma unroll
    for (int p = 0; p < NTOK; ++p)
        sc[p] = tok[p][0]*wq4[0] + tok[p][1]*wq4[1]
              + tok[p][2]*wq4[2] + tok[p][3]*wq4[3];
    #pragma unroll
    for (int m = 1; m < 32; m <<= 1) {
        #pragma unroll
        for (int p = 0; p < NTOK; ++p) sc[p] += __shfl_xor(sc[p], m);
    }
    const float isd = 0.08838834764831845f;   // 1/sqrt(128)
    float mx = -1e30f;
    #pragma unroll
    for (int p = 0; p < NTOK; ++p) {
        sc[p] = val[p] ? sc[p] * isd : -1e30f;
        mx = fmaxf(mx, sc[p]);
    }
    float se = 0.f;
    #pragma unroll
    for (int p = 0; p < NTOK; ++p) { sc[p] = __expf(sc[p] - mx); se += sc[p]; }
    const float inv = 1.f / se;
    float a0=0.f, a1=0.f, a2=0.f, a3=0.f;
    #pragma unroll
    for (int p = 0; p < NTOK; ++p) {
        float a = sc[p] * inv;
        a0 += a * tok[p][0]; a1 += a * tok[p][1];
        a2 += a * tok[p][2]; a3 += a * tok[p][3];
    }
    uint2 o;
    o.x = pk_bf16(a0, a1);
    o.y = pk_bf16(a2, a3);
    *(uint2*)(pooled + (size_t)hop * DIM + l * 4) = o;
}

// ===== head: GEMM1 + (fused bias/ReLU/LN in registers) + GEMM2 =====
__global__ __launch_bounds__(256, 3)
void head_k(const unsigned short* __restrict__ pooled,
            const unsigned short* __restrict__ w1t,     // bf16 [512][128]
            const float* __restrict__ b1,
            const float* __restrict__ gamma,
            const float* __restrict__ beta,
            const unsigned short* __restrict__ w2t,     // bf16 [64][512]
            const float* __restrict__ b2,
            float* __restrict__ out,
            int H)
{
    __shared__ unsigned short Hsm[HEAD_HOPS][DFF + 8];  // stride 520
    __shared__ float part[2][16][4][2];                 // [ht][row][wave][sum,ssq]

    const int t    = threadIdx.x;
    const int lane = t & 63;
    const int w    = t >> 6;
    const int row  = lane & 15;
    const int quad = lane >> 4;
    const int hop0 = blockIdx.x * HEAD_HOPS;

    // -------- GEMM1: A=W1T rows (out-dims), B=pooled^T (hops); all acc live --------
    float4v acc[8][2];
    #pragma unroll
    for (int mt = 0; mt < 8; ++mt) {
        acc[mt][0] = (float4v){0.f, 0.f, 0.f, 0.f};
        acc[mt][1] = (float4v){0.f, 0.f, 0.f, 0.f};
    }
    {
        short8 bfr[2][4];
        #pragma unroll
        for (int ks = 0; ks < 4; ++ks) {
            const int k0 = ks * 32 + quad * 8;
            #pragma unroll
            for (int ht = 0; ht < 2; ++ht) {
                int hp = hop0 + ht * 16 + row;
                if (hp >= H) hp = H - 1;      // clamped read; out store is guarded
                bfr[ht][ks] = *(const short8*)(pooled + (size_t)hp * DIM + k0);
            }
        }
        #pragma unroll
        for (int mt = 0; mt < 8; ++mt) {
            const unsigned short* wrow = w1t + (size_t)(w * 128 + mt * 16 + row) * DIM;
            #pragma unroll
            for (int ks = 0; ks < 4; ++ks) {
                short8 afr = *(const short8*)(wrow + ks * 32 + quad * 8);
                acc[mt][0] = __builtin_amdgcn_mfma_f32_16x16x32_bf16(afr, bfr[0][ks], acc[mt][0], 0, 0, 0);
                acc[mt][1] = __builtin_amdgcn_mfma_f32_16x16x32_bf16(afr, bfr[1][ks], acc[mt][1], 0, 0, 0);
            }
        }
    }
    // -------- pass 1: bias + ReLU in registers, LN stats --------
    float sum0 = 0.f, ssq0 = 0.f, sum1 = 0.f, ssq1 = 0.f;
    #pragma unroll
    for (int mt = 0; mt < 8; ++mt) {
        const int nb = w * 128 + mt * 16 + quad * 4;
        const float4v bias = *(const float4v*)(b1 + nb);
        #pragma unroll
        for (int r = 0; r < 4; ++r) {
            float v0 = fmaxf(acc[mt][0][r] + bias[r], 0.f);
            float v1 = fmaxf(acc[mt][1][r] + bias[r], 0.f);
            acc[mt][0][r] = v0;  sum0 += v0;  ssq0 += v0 * v0;
            acc[mt][1][r] = v1;  sum1 += v1;  ssq1 += v1 * v1;
        }
    }
    #pragma unroll
    for (int m = 16; m <= 32; m <<= 1) {       // reduce across the 4 quads
        sum0 += __shfl_xor(sum0, m);  ssq0 += __shfl_xor(ssq0, m);
        sum1 += __shfl_xor(sum1, m);  ssq1 += __shfl_xor(ssq1, m);
    }
    if (lane < 16) {
        part[0][row][w][0] = sum0;  part[0][row][w][1] = ssq0;
        part[1][row][w][0] = sum1;  part[1][row][w][1] = ssq1;
    }
    __syncthreads();
    float mu[2], rs[2];
    #pragma unroll
    for (int ht = 0; ht < 2; ++ht) {
        float S = 0.f, Q = 0.f;
        #pragma unroll
        for (int ww = 0; ww < 4; ++ww) {
            S += part[ht][row][ww][0];
            Q += part[ht][row][ww][1];
        }
        const float invn = 1.f / (float)DFF;
        mu[ht] = S * invn;
        float var = Q * invn - mu[ht] * mu[ht];
        rs[ht] = rsqrtf(var + 1e-5f);
    }
    // -------- pass 2: normalize fp32 regs, pack bf16, single LDS write --------
    #pragma unroll
    for (int mt = 0; mt < 8; ++mt) {
        const int nb = w * 128 + mt * 16 + quad * 4;
        const float4v g4  = *(const float4v*)(gamma + nb);
        const float4v be4 = *(const float4v*)(beta + nb);
        #pragma unroll
        for (int ht = 0; ht < 2; ++ht) {
            float o[4];
            #pragma unroll
            for (int r = 0; r < 4; ++r) {
                float tg = rs[ht] * g4[r];
                o[r] = acc[mt][ht][r] * tg + (be4[r] - mu[ht] * tg);
            }
            uint2 p;
            p.x = pk_bf16(o[0], o[1]);
            p.y = pk_bf16(o[2], o[3]);
            *(uint2*)&Hsm[ht * 16 + row][nb] = p;
        }
    }
    __syncthreads();

    // -------- GEMM2 (A=Hs [hop][k] LDS, B=w2t [tt][k] global) --------
    {
        float4v acc2[2];
        acc2[0] = (float4v){0.f,0.f,0.f,0.f};
        acc2[1] = (float4v){0.f,0.f,0.f,0.f};
        #pragma unroll
        for (int ks = 0; ks < 16; ++ks) {
            const int k0 = ks * 32 + quad * 8;
            short8 bfr = *(const short8*)(w2t + (size_t)(w * 16 + row) * DFF + k0);
            #pragma unroll
            for (int mt = 0; mt < 2; ++mt) {
                short8 afr = *(const short8*)&Hsm[mt * 16 + row][k0];
                acc2[mt] = __builtin_amdgcn_mfma_f32_16x16x32_bf16(
                    afr, bfr, acc2[mt], 0, 0, 0);
            }
        }
        const float bb = b2[w * 16 + row];
        #pragma unroll
        for (int mt = 0; mt < 2; ++mt) {
            #pragma unroll
            for (int r = 0; r < 4; ++r) {
                int hop = hop0 + mt * 16 + quad * 4 + r;
                if (hop < H)
                    out[(size_t)hop * TTW + w * 16 + row] = acc2[mt][r] + bb;
            }
        }
    }
}

extern "C" void kernel_launch(void* const* d_in, const int* in_sizes, int n_in,
                              void* d_out, int out_size, void* d_ws, size_t ws_size,
                              hipStream_t stream) {
    const float* hf    = (const float*)d_in[0];
    const float* w_q   = (const float*)d_in[1];
    const float* W1    = (const float*)d_in[2];
    const float* b1    = (const float*)d_in[3];
    const float* gamma = (const float*)d_in[4];
    const float* beta  = (const float*)d_in[5];
    const float* W2    = (const float*)d_in[6];
    const float* b2    = (const float*)d_in[7];
    const int* pi      = (const int*)d_in[8];
    const int* stats   = (const int*)d_in[9];
    const int* po      = (const int*)d_in[10];
    float* out         = (float*)d_out;

    const int n_hf = in_sizes[0];           // N_NODES*128
    const int H    = in_sizes[10];
    const int n_pk = H * NPI;
    const int Hpad = ((H + HEAD_HOPS - 1) / HEAD_HOPS) * HEAD_HOPS;

    // ws layout (256B-aligned chunks)
    char* ws = (char*)d_ws;
    unsigned short* w1t    = (unsigned short*)ws;                       // 128KB
    unsigned short* w2t    = (unsigned short*)(ws + 131072);            // 64KB
    unsigned short* hf2    = (unsigned short*)(ws + 196608);            // n_hf*2
    size_t off_cp = 196608 + ((size_t)n_hf * 2 + 255) / 256 * 256;
    int*            cpack  = (int*)(ws + off_cp);                       // n_pk*4
    size_t off_pl = off_cp + ((size_t)n_pk * 4 + 255) / 256 * 256;
    unsigned short* pooled = (unsigned short*)(ws + off_pl);            // Hpad*128*2

    const int B_HF = (n_hf + 1023) / 1024;
    const int B_PK = (n_pk + 1023) / 1024;
    const int prep_blocks = B_HF + 96 + B_PK;

    hipLaunchKernelGGL(prep_k, dim3(prep_blocks), dim3(256), 0, stream,
                       hf, W1, W2, pi, stats, hf2, w1t, w2t, cpack,
                       n_hf, B_HF, n_pk);
    hipLaunchKernelGGL(pool_k, dim3((H + POOL_HOPS - 1) / POOL_HOPS), dim3(256), 0, stream,
                       hf2, w_q, cpack, po, pooled, H);
    hipLaunchKernelGGL(head_k, dim3(Hpad / HEAD_HOPS), dim3(256), 0, stream,
                       pooled, w1t, b1, gamma, beta, w2t, b2, out, H);
}

// Round 6
// 212.406 us; speedup vs baseline: 1.1818x; 1.0627x over previous
//
#include <hip/hip_runtime.h>
#include <hip/hip_bf16.h>
#include <math.h>

#define DIM 128
#define DFF 512
#define TTW 64
#define NPI 8
#define NTOK 9
#define TILE_H 32

typedef __attribute__((ext_vector_type(8))) short short8;
typedef __attribute__((ext_vector_type(4))) float float4v;

__device__ __forceinline__ float bf16lo_f32(unsigned u) {
    union { unsigned u; float f; } v; v.u = u << 16;
    return v.f;
}
__device__ __forceinline__ float bf16hi_f32(unsigned u) {
    union { unsigned u; float f; } v; v.u = u & 0xffff0000u;
    return v.f;
}
__device__ __forceinline__ unsigned pk_bf16(float a, float b) {  // -> a | b<<16
    __hip_bfloat162 h = __float22bfloat162_rn(float2{a, b});
    union { __hip_bfloat162 h; unsigned u; } cv; cv.h = h;
    return cv.u;
}

// ================= prep: all-coalesced weight/feature conversion =================
__global__ __launch_bounds__(256)
void prep_k(const float* __restrict__ hf, const float* __restrict__ W1,
            const float* __restrict__ W2, const int* __restrict__ pi,
            const int* __restrict__ stats,
            unsigned short* __restrict__ hf2, unsigned short* __restrict__ w1t,
            unsigned short* __restrict__ w2t, int* __restrict__ cpack,
            int n_hf, int B_HF, int n_pk)
{
    __shared__ float tile[32][33];
    const int b = blockIdx.x, t = threadIdx.x;
    if (b < B_HF) {
        int i = (b * 256 + t) * 4;
        if (i < n_hf) {
            float4v v = *(const float4v*)(hf + i);
            uint2 o;
            o.x = pk_bf16(v[0], v[1]);
            o.y = pk_bf16(v[2], v[3]);
            *(uint2*)(hf2 + i) = o;
        }
    } else if (b < B_HF + 64) {
        const int tb = b - B_HF;            // W1 [128][512] -> w1t bf16 [512][128]
        const int r0 = (tb & 3) * 32, c0 = (tb >> 2) * 32;
        const int ty = t >> 3, tx = t & 7;
        *(float4v*)&tile[ty][tx * 4] = *(const float4v*)(W1 + (r0 + ty) * DFF + c0 + tx * 4);
        __syncthreads();
        uint2 o;
        o.x = pk_bf16(tile[tx * 4 + 0][ty], tile[tx * 4 + 1][ty]);
        o.y = pk_bf16(tile[tx * 4 + 2][ty], tile[tx * 4 + 3][ty]);
        *(uint2*)(w1t + (c0 + ty) * DIM + r0 + tx * 4) = o;
    } else if (b < B_HF + 96) {
        const int tb = b - B_HF - 64;       // W2 [512][64] -> w2t bf16 [64][512]
        const int r0 = (tb & 15) * 32, c0 = (tb >> 4) * 32;
        const int ty = t >> 3, tx = t & 7;
        *(float4v*)&tile[ty][tx * 4] = *(const float4v*)(W2 + (r0 + ty) * TTW + c0 + tx * 4);
        __syncthreads();
        uint2 o;
        o.x = pk_bf16(tile[tx * 4 + 0][ty], tile[tx * 4 + 1][ty]);
        o.y = pk_bf16(tile[tx * 4 + 2][ty], tile[tx * 4 + 3][ty]);
        *(uint2*)(w2t + (c0 + ty) * DFF + r0 + tx * 4) = o;
    } else {
        const int pb = b - (B_HF + 96);
        int i = (pb * 256 + t) * 4;
        if (i < n_pk) {
            int4 p = *(const int4*)(pi + i);
            int4 s = *(const int4*)(stats + i);
            int4 o;
            o.x = p.x | (s.x == -1 ? (int)0x80000000 : 0);
            o.y = p.y | (s.y == -1 ? (int)0x80000000 : 0);
            o.z = p.z | (s.z == -1 ? (int)0x80000000 : 0);
            o.w = p.w | (s.w == -1 ? (int)0x80000000 : 0);
            *(int4*)(cpack + i) = o;
        }
    }
}

// ===== fused: gather+pool -> GEMM1 -> reg-LN -> GEMM2 (one kernel, full overlap) =====
__global__ __launch_bounds__(256, 3)
void fused_k(const unsigned short* __restrict__ hf2,
             const float* __restrict__ w_q,
             const int* __restrict__ cpack,
             const int* __restrict__ po,
             const unsigned short* __restrict__ w1t,     // bf16 [512][128]
             const float* __restrict__ b1,
             const float* __restrict__ gamma,
             const float* __restrict__ beta,
             const unsigned short* __restrict__ w2t,     // bf16 [64][512]
             const float* __restrict__ b2,
             float* __restrict__ out,
             int H)
{
    __shared__ unsigned short Apool[TILE_H][DIM + 8];   // stride 272 B
    __shared__ unsigned short Hsm[TILE_H][DFF + 8];     // stride 1040 B
    __shared__ float part[2][16][4][2];                 // [ht][row][wave][sum,ssq]

    const int t    = threadIdx.x;
    const int lane = t & 63;
    const int w    = t >> 6;
    const int row  = lane & 15;
    const int quad = lane >> 4;
    const int hop0 = blockIdx.x * TILE_H;

    // -------- Phase 1: gather + masked attention pooling (32 lanes/hop) --------
    {
        const int g = t >> 5, l = t & 31;       // lane l owns dims 4l..4l+3
        const float4v wq4 = *(const float4v*)(w_q + l * 4);
        #pragma unroll
        for (int it = 0; it < 4; ++it) {
            const int hl = g + it * 8;
            const int hop = hop0 + hl;
            uint2 o = {0u, 0u};
            if (hop < H) {
                int idx[NTOK]; bool val[NTOK];
                int4 c0 = *(const int4*)(cpack + hop * NPI);
                int4 c1 = *(const int4*)(cpack + hop * NPI + 4);
                idx[0]=c0.x & 0x7fffffff; val[0]=c0.x >= 0;
                idx[1]=c0.y & 0x7fffffff; val[1]=c0.y >= 0;
                idx[2]=c0.z & 0x7fffffff; val[2]=c0.z >= 0;
                idx[3]=c0.w & 0x7fffffff; val[3]=c0.w >= 0;
                idx[4]=c1.x & 0x7fffffff; val[4]=c1.x >= 0;
                idx[5]=c1.y & 0x7fffffff; val[5]=c1.y >= 0;
                idx[6]=c1.z & 0x7fffffff; val[6]=c1.z >= 0;
                idx[7]=c1.w & 0x7fffffff; val[7]=c1.w >= 0;
                idx[8]=po[hop]; val[8]=true;
                uint2 tu[NTOK];
                #pragma unroll
                for (int p = 0; p < NTOK; ++p)
                    tu[p] = *(const uint2*)(hf2 + (size_t)idx[p] * DIM + l * 4);
                float tok[NTOK][4];
                #pragma unroll
                for (int p = 0; p < NTOK; ++p) {
                    tok[p][0] = bf16lo_f32(tu[p].x);
                    tok[p][1] = bf16hi_f32(tu[p].x);
                    tok[p][2] = bf16lo_f32(tu[p].y);
                    tok[p][3] = bf16hi_f32(tu[p].y);
                }
                float sc[NTOK];
                #pragma unroll
                for (int p = 0; p < NTOK; ++p)
                    sc[p] = tok[p][0]*wq4[0] + tok[p][1]*wq4[1]
                          + tok[p][2]*wq4[2] + tok[p][3]*wq4[3];
                #pragma unroll
                for (int m = 1; m < 32; m <<= 1) {
                    #pragma unroll
                    for (int p = 0; p < NTOK; ++p) sc[p] += __shfl_xor(sc[p], m);
                }
                const float isd = 0.08838834764831845f;   // 1/sqrt(128)
                float mx = -1e30f;
                #pragma unroll
                for (int p = 0; p < NTOK; ++p) {
                    sc[p] = val[p] ? sc[p] * isd : -1e30f;
                    mx = fmaxf(mx, sc[p]);
                }
                float se = 0.f;
                #pragma unroll
                for (int p = 0; p < NTOK; ++p) { sc[p] = __expf(sc[p] - mx); se += sc[p]; }
                const float inv = 1.f / se;
                float a0=0.f, a1=0.f, a2=0.f, a3=0.f;
                #pragma unroll
                for (int p = 0; p < NTOK; ++p) {
                    float a = sc[p] * inv;
                    a0 += a * tok[p][0]; a1 += a * tok[p][1];
                    a2 += a * tok[p][2]; a3 += a * tok[p][3];
                }
                o.x = pk_bf16(a0, a1);
                o.y = pk_bf16(a2, a3);
            }
            *(uint2*)&Apool[hl][l * 4] = o;
        }
    }
    __syncthreads();

    // -------- GEMM1: A=W1T rows (out-dims), B=Apool^T (hops); all acc live --------
    float4v acc[8][2];
    #pragma unroll
    for (int mt = 0; mt < 8; ++mt) {
        acc[mt][0] = (float4v){0.f, 0.f, 0.f, 0.f};
        acc[mt][1] = (float4v){0.f, 0.f, 0.f, 0.f};
    }
    {
        short8 bfr[2][4];
        #pragma unroll
        for (int ks = 0; ks < 4; ++ks) {
            const int k0 = ks * 32 + quad * 8;
            #pragma unroll
            for (int ht = 0; ht < 2; ++ht)
                bfr[ht][ks] = *(const short8*)&Apool[ht * 16 + row][k0];
        }
        #pragma unroll
        for (int mt = 0; mt < 8; ++mt) {
            const unsigned short* wrow = w1t + (size_t)(w * 128 + mt * 16 + row) * DIM;
            #pragma unroll
            for (int ks = 0; ks < 4; ++ks) {
                short8 afr = *(const short8*)(wrow + ks * 32 + quad * 8);
                acc[mt][0] = __builtin_amdgcn_mfma_f32_16x16x32_bf16(afr, bfr[0][ks], acc[mt][0], 0, 0, 0);
                acc[mt][1] = __builtin_amdgcn_mfma_f32_16x16x32_bf16(afr, bfr[1][ks], acc[mt][1], 0, 0, 0);
            }
        }
    }
    // -------- pass 1: bias + ReLU in registers, LN stats --------
    float sum0 = 0.f, ssq0 = 0.f, sum1 = 0.f, ssq1 = 0.f;
    #pragma unroll
    for (int mt = 0; mt < 8; ++mt) {
        const int nb = w * 128 + mt * 16 + quad * 4;
        const float4v bias = *(const float4v*)(b1 + nb);
        #pragma unroll
        for (int r = 0; r < 4; ++r) {
            float v0 = fmaxf(acc[mt][0][r] + bias[r], 0.f);
            float v1 = fmaxf(acc[mt][1][r] + bias[r], 0.f);
            acc[mt][0][r] = v0;  sum0 += v0;  ssq0 += v0 * v0;
            acc[mt][1][r] = v1;  sum1 += v1;  ssq1 += v1 * v1;
        }
    }
    #pragma unroll
    for (int m = 16; m <= 32; m <<= 1) {       // reduce across the 4 quads
        sum0 += __shfl_xor(sum0, m);  ssq0 += __shfl_xor(ssq0, m);
        sum1 += __shfl_xor(sum1, m);  ssq1 += __shfl_xor(ssq1, m);
    }
    if (lane < 16) {
        part[0][row][w][0] = sum0;  part[0][row][w][1] = ssq0;
        part[1][row][w][0] = sum1;  part[1][row][w][1] = ssq1;
    }
    __syncthreads();
    float mu[2], rs[2];
    #pragma unroll
    for (int ht = 0; ht < 2; ++ht) {
        float S = 0.f, Q = 0.f;
        #pragma unroll
        for (int ww = 0; ww < 4; ++ww) {
            S += part[ht][row][ww][0];
            Q += part[ht][row][ww][1];
        }
        const float invn = 1.f / (float)DFF;
        mu[ht] = S * invn;
        float var = Q * invn - mu[ht] * mu[ht];
        rs[ht] = rsqrtf(var + 1e-5f);
    }
    // -------- pass 2: normalize fp32 regs, pack bf16, single LDS write --------
    #pragma unroll
    for (int mt = 0; mt < 8; ++mt) {
        const int nb = w * 128 + mt * 16 + quad * 4;
        const float4v g4  = *(const float4v*)(gamma + nb);
        const float4v be4 = *(const float4v*)(beta + nb);
        #pragma unroll
        for (int ht = 0; ht < 2; ++ht) {
            float o[4];
            #pragma unroll
            for (int r = 0; r < 4; ++r) {
                float tg = rs[ht] * g4[r];
                o[r] = acc[mt][ht][r] * tg + (be4[r] - mu[ht] * tg);
            }
            uint2 p;
            p.x = pk_bf16(o[0], o[1]);
            p.y = pk_bf16(o[2], o[3]);
            *(uint2*)&Hsm[ht * 16 + row][nb] = p;
        }
    }
    __syncthreads();

    // -------- GEMM2 (A=Hs [hop][k] LDS, B=w2t [tt][k] global) --------
    {
        float4v acc2[2];
        acc2[0] = (float4v){0.f,0.f,0.f,0.f};
        acc2[1] = (float4v){0.f,0.f,0.f,0.f};
        #pragma unroll
        for (int ks = 0; ks < 16; ++ks) {
            const int k0 = ks * 32 + quad * 8;
            short8 bfr = *(const short8*)(w2t + (size_t)(w * 16 + row) * DFF + k0);
            #pragma unroll
            for (int mt = 0; mt < 2; ++mt) {
                short8 afr = *(const short8*)&Hsm[mt * 16 + row][k0];
                acc2[mt] = __builtin_amdgcn_mfma_f32_16x16x32_bf16(
                    afr, bfr, acc2[mt], 0, 0, 0);
            }
        }
        const float bb = b2[w * 16 + row];
        #pragma unroll
        for (int mt = 0; mt < 2; ++mt) {
            #pragma unroll
            for (int r = 0; r < 4; ++r) {
                int hop = hop0 + mt * 16 + quad * 4 + r;
                if (hop < H)
                    out[(size_t)hop * TTW + w * 16 + row] = acc2[mt][r] + bb;
            }
        }
    }
}

extern "C" void kernel_launch(void* const* d_in, const int* in_sizes, int n_in,
                              void* d_out, int out_size, void* d_ws, size_t ws_size,
                              hipStream_t stream) {
    const float* hf    = (const float*)d_in[0];
    const float* w_q   = (const float*)d_in[1];
    const float* W1    = (const float*)d_in[2];
    const float* b1    = (const float*)d_in[3];
    const float* gamma = (const float*)d_in[4];
    const float* beta  = (const float*)d_in[5];
    const float* W2    = (const float*)d_in[6];
    const float* b2    = (const float*)d_in[7];
    const int* pi      = (const int*)d_in[8];
    const int* stats   = (const int*)d_in[9];
    const int* po      = (const int*)d_in[10];
    float* out         = (float*)d_out;

    const int n_hf = in_sizes[0];           // N_NODES*128
    const int H    = in_sizes[10];
    const int n_pk = H * NPI;

    // ws layout (256B-aligned chunks)
    char* ws = (char*)d_ws;
    unsigned short* w1t    = (unsigned short*)ws;                       // 128KB
    unsigned short* w2t    = (unsigned short*)(ws + 131072);            // 64KB
    unsigned short* hf2    = (unsigned short*)(ws + 196608);            // n_hf*2
    size_t off_cp = 196608 + ((size_t)n_hf * 2 + 255) / 256 * 256;
    int*            cpack  = (int*)(ws + off_cp);                       // n_pk*4

    const int B_HF = (n_hf + 1023) / 1024;
    const int B_PK = (n_pk + 1023) / 1024;
    const int prep_blocks = B_HF + 96 + B_PK;

    hipLaunchKernelGGL(prep_k, dim3(prep_blocks), dim3(256), 0, stream,
                       hf, W1, W2, pi, stats, hf2, w1t, w2t, cpack,
                       n_hf, B_HF, n_pk);
    hipLaunchKernelGGL(fused_k, dim3((H + TILE_H - 1) / TILE_H), dim3(256), 0, stream,
                       hf2, w_q, cpack, po, w1t, b1, gamma, beta, w2t, b2, out, H);
}